// Round 1
// baseline (395.403 us; speedup 1.0000x reference)
//
#include <hip/hip_runtime.h>
#include <hip/hip_bf16.h>
#include <math.h>

typedef __bf16 bf16_t;
typedef __bf16 bf16x8 __attribute__((ext_vector_type(8)));
typedef __bf16 bf16x2 __attribute__((ext_vector_type(2)));
typedef float f32x4 __attribute__((ext_vector_type(4)));

#define NH 16
#define T 4000
#define D 64
#define WINB 128

// ---------------- Kernel 1: local window attention ----------------
// One block = 64 q rows of one (n,h). Window = 3 chunks of 128 local keys
// + 1 global key (token 0), online softmax, bf16 MFMA for QK^T and PV.
__global__ __launch_bounds__(256, 2)
void local_attn(const float* __restrict__ q, const float* __restrict__ k,
                const float* __restrict__ v, const float* __restrict__ mask,
                float* __restrict__ out) {
  const int qb   = blockIdx.x;                 // 0..63  (64-row q block)
  const int zn   = blockIdx.z;
  const int bh   = zn * NH + blockIdx.y;
  const int tid  = threadIdx.x;
  const int wid  = tid >> 6;
  const int lane = tid & 63;
  const int quad = lane >> 4;
  const int l15  = lane & 15;
  const int win  = qb >> 1;
  const int qbase = qb * 64;

  __shared__ __align__(16) bf16_t Qs[64][72];      // +8 pad: breaks 128B stride aliasing
  __shared__ __align__(16) bf16_t Ks[128][72];
  __shared__ __align__(16) bf16_t Vts[64][136];    // V transposed: Vts[d][kk]
  __shared__ __align__(16) bf16_t Ps[4][16][136];  // per-wave P staging (C->A layout)
  __shared__ float maskc[128];
  __shared__ float gsc[64];
  __shared__ float K0s[64];
  __shared__ float V0s[64];

  const size_t inbase = (size_t)bh * T * D;

  // ---- stage Q (bf16), K0/V0 (fp32) ----
  for (int i = 0; i < 8; i++) {
    int idx = i * 256 + tid;
    int row = idx >> 5, dp = idx & 31;
    int tok = qbase + row;
    float2 val = make_float2(0.f, 0.f);
    if (tok < T) val = *(const float2*)(q + inbase + (size_t)tok * D + dp * 2);
    bf16x2 bv; bv.x = (bf16_t)val.x; bv.y = (bf16_t)val.y;
    *(bf16x2*)&Qs[row][dp * 2] = bv;
  }
  if (tid < 64) { K0s[tid] = k[inbase + tid]; V0s[tid] = v[inbase + tid]; }
  __syncthreads();

  // ---- global-key scores per q row (finite init for online softmax) ----
  if (tid < 64) {
    float dot = 0.f;
    for (int dd = 0; dd < 64; dd++) dot += (float)Qs[tid][dd] * K0s[dd];
    gsc[tid] = dot * 0.125f + mask[(size_t)zn * T];  // mg uses m[:,0]
  }
  __syncthreads();

  // ---- init online-softmax state from global key ----
  float m_st[4], l_st[4];
  f32x4 acc[4];
  for (int r = 0; r < 4; r++) {
    m_st[r] = gsc[wid * 16 + quad * 4 + r];
    l_st[r] = 1.0f;
  }
  for (int dt = 0; dt < 4; dt++) {
    float v0 = V0s[dt * 16 + l15];
    acc[dt] = (f32x4){v0, v0, v0, v0};
  }

  // ---- 3 chunks of 128 local keys ----
  for (int c = 0; c < 3; c++) {
    const int kbase = (win + c - 1) * WINB;
    __syncthreads();   // protect Ks/Vts against previous chunk's readers
    // stage K chunk (row-major bf16)
    for (int i = 0; i < 16; i++) {
      int idx = i * 256 + tid;
      int row = idx >> 5, dp = idx & 31;
      int kt = kbase + row;
      float2 val = make_float2(0.f, 0.f);
      if (kt >= 1 && kt < T) val = *(const float2*)(k + inbase + (size_t)kt * D + dp * 2);
      bf16x2 bv; bv.x = (bf16_t)val.x; bv.y = (bf16_t)val.y;
      *(bf16x2*)&Ks[row][dp * 2] = bv;
    }
    // stage V chunk transposed: Vts[d][kk]
    for (int i = 0; i < 16; i++) {
      int idx = i * 256 + tid;
      int d = idx & 63, kp = idx >> 6;
      int ktl = kp * 2, kt = kbase + ktl;
      float v0 = (kt   >= 1 && kt   < T) ? v[inbase + (size_t)kt * D + d]       : 0.f;
      float v1 = (kt+1 >= 1 && kt+1 < T) ? v[inbase + (size_t)(kt + 1) * D + d] : 0.f;
      bf16x2 bv; bv.x = (bf16_t)v0; bv.y = (bf16_t)v1;
      *(bf16x2*)&Vts[d][ktl] = bv;
    }
    if (tid < 128) {
      int kt = kbase + tid;   // token 0 excluded from local window (m_loc[0]=MIN)
      maskc[tid] = (kt >= 1 && kt < T) ? mask[(size_t)zn * T + kt] : -INFINITY;
    }
    __syncthreads();

    // ---- S = Q·K^T : this wave's 16 q rows × 128 keys ----
    f32x4 s[8];
    for (int t = 0; t < 8; t++) s[t] = (f32x4){0.f, 0.f, 0.f, 0.f};
    for (int kb = 0; kb < 2; kb++) {
      bf16x8 a = *(const bf16x8*)&Qs[wid * 16 + l15][kb * 32 + quad * 8];
      for (int t = 0; t < 8; t++) {
        bf16x8 b = *(const bf16x8*)&Ks[t * 16 + l15][kb * 32 + quad * 8];
        s[t] = __builtin_amdgcn_mfma_f32_16x16x32_bf16(a, b, s[t], 0, 0, 0);
      }
    }
    float mv[8];
    for (int t = 0; t < 8; t++) mv[t] = maskc[t * 16 + l15];
    for (int t = 0; t < 8; t++)
      for (int r = 0; r < 4; r++)
        s[t][r] = s[t][r] * 0.125f + mv[t];

    // ---- online softmax (row = quad*4+r, replicated over 16 lanes of quad) ----
    for (int r = 0; r < 4; r++) {
      float rm = s[0][r];
      for (int t = 1; t < 8; t++) rm = fmaxf(rm, s[t][r]);
      rm = fmaxf(rm, __shfl_xor(rm, 1));
      rm = fmaxf(rm, __shfl_xor(rm, 2));
      rm = fmaxf(rm, __shfl_xor(rm, 4));
      rm = fmaxf(rm, __shfl_xor(rm, 8));
      float m_new = fmaxf(m_st[r], rm);
      float alpha = __expf(m_st[r] - m_new);
      float rs = 0.f;
      for (int t = 0; t < 8; t++) {
        float p = __expf(s[t][r] - m_new);
        Ps[wid][quad * 4 + r][t * 16 + l15] = (bf16_t)p;  // C-layout -> row-major
        rs += p;
      }
      rs += __shfl_xor(rs, 1);
      rs += __shfl_xor(rs, 2);
      rs += __shfl_xor(rs, 4);
      rs += __shfl_xor(rs, 8);
      l_st[r] = l_st[r] * alpha + rs;
      m_st[r] = m_new;
      for (int dt = 0; dt < 4; dt++) acc[dt][r] *= alpha;
    }
    __syncthreads();   // Ps visible

    // ---- O += P·V ----
    for (int kk = 0; kk < 4; kk++) {
      bf16x8 a = *(const bf16x8*)&Ps[wid][l15][kk * 32 + quad * 8];  // A-layout read
      for (int dt = 0; dt < 4; dt++) {
        bf16x8 b = *(const bf16x8*)&Vts[dt * 16 + l15][kk * 32 + quad * 8];
        acc[dt] = __builtin_amdgcn_mfma_f32_16x16x32_bf16(a, b, acc[dt], 0, 0, 0);
      }
    }
  }

  // ---- epilogue ----
  for (int r = 0; r < 4; r++) {
    int tok = qbase + wid * 16 + quad * 4 + r;
    if (tok < T) {
      float inv = 1.0f / l_st[r];
      size_t ob = inbase + (size_t)tok * D + l15;
      out[ob]      = acc[0][r] * inv;
      out[ob + 16] = acc[1][r] * inv;
      out[ob + 32] = acc[2][r] * inv;
      out[ob + 48] = acc[3][r] * inv;
    }
  }
}

// ---------------- Kernel 2a: token-0 global attention, split-K partials ----
__global__ __launch_bounds__(256)
void global_attn_partial(const float* __restrict__ q, const float* __restrict__ k,
                         const float* __restrict__ v, const float* __restrict__ mask,
                         float* __restrict__ ws) {
  const int s  = blockIdx.x;                 // split 0..7, 500 keys each
  const int zn = blockIdx.z;
  const int bh = zn * NH + blockIdx.y;
  const int tid = threadIdx.x;
  __shared__ __align__(16) float q0[64];
  __shared__ float sc[500];
  __shared__ float wred[8];
  __shared__ float racc[256];

  const size_t inbase = (size_t)bh * T * D;
  if (tid < 64) q0[tid] = q[inbase + tid];
  __syncthreads();

  const int j0 = s * 500;
  float lmax = -INFINITY;
  const float4* q4 = (const float4*)q0;
  for (int jl = tid; jl < 500; jl += 256) {
    const float4* kr = (const float4*)(k + inbase + (size_t)(j0 + jl) * D);
    float dot = 0.f;
    for (int dd = 0; dd < 16; dd++) {
      float4 a = q4[dd], b = kr[dd];
      dot += a.x * b.x + a.y * b.y + a.z * b.z + a.w * b.w;
    }
    float sv = dot * 0.125f + mask[(size_t)zn * T + j0 + jl];
    sc[jl] = sv;
    lmax = fmaxf(lmax, sv);
  }
  for (int off = 32; off; off >>= 1) lmax = fmaxf(lmax, __shfl_xor(lmax, off));
  int wid = tid >> 6, lane = tid & 63;
  if (!lane) wred[wid] = lmax;
  __syncthreads();
  float m_p = fmaxf(fmaxf(wred[0], wred[1]), fmaxf(wred[2], wred[3]));
  float lsum = 0.f;
  for (int jl = tid; jl < 500; jl += 256) {
    float e = __expf(sc[jl] - m_p);
    sc[jl] = e;
    lsum += e;
  }
  for (int off = 32; off; off >>= 1) lsum += __shfl_xor(lsum, off);
  if (!lane) wred[4 + wid] = lsum;
  __syncthreads();
  float l_p = wred[4] + wred[5] + wred[6] + wred[7];

  int d = tid & 63, part = tid >> 6;
  float a = 0.f;
  for (int jl = part; jl < 500; jl += 4)
    a += sc[jl] * v[inbase + (size_t)(j0 + jl) * D + d];
  racc[tid] = a;
  __syncthreads();
  if (tid < 64) {
    float tot = racc[tid] + racc[tid + 64] + racc[tid + 128] + racc[tid + 192];
    float* o = ws + (size_t)(bh * 8 + s) * 66;
    if (tid == 0) { o[0] = m_p; o[1] = l_p; }
    o[2 + tid] = tot;
  }
}

// ---------------- Kernel 2b: combine split-K partials for token 0 ----------
__global__ __launch_bounds__(64)
void global_attn_combine(const float* __restrict__ ws, float* __restrict__ out) {
  const int bh = blockIdx.x;
  const int d = threadIdx.x;
  float m = -INFINITY;
  for (int s = 0; s < 8; s++) m = fmaxf(m, ws[(size_t)(bh * 8 + s) * 66]);
  float l = 0.f, a = 0.f;
  for (int s = 0; s < 8; s++) {
    const float* o = ws + (size_t)(bh * 8 + s) * 66;
    float f = __expf(o[0] - m);
    l += f * o[1];
    a += f * o[2 + d];
  }
  out[(size_t)bh * T * D + d] = a / l;
}

extern "C" void kernel_launch(void* const* d_in, const int* in_sizes, int n_in,
                              void* d_out, int out_size, void* d_ws, size_t ws_size,
                              hipStream_t stream) {
  const float* q    = (const float*)d_in[0];
  const float* k    = (const float*)d_in[1];
  const float* v    = (const float*)d_in[2];
  const float* mask = (const float*)d_in[3];
  float* out = (float*)d_out;
  float* ws  = (float*)d_ws;
  int n = in_sizes[3] / T;   // attention_mask is (n,1,1,T)

  dim3 g1(64, NH, n);
  local_attn<<<g1, 256, 0, stream>>>(q, k, v, mask, out);
  dim3 g2(8, NH, n);
  global_attn_partial<<<g2, 256, 0, stream>>>(q, k, v, mask, ws);
  global_attn_combine<<<dim3(n * NH), 64, 0, stream>>>(ws, out);
}